// Round 4
// baseline (4297.092 us; speedup 1.0000x reference)
//
#include <hip/hip_runtime.h>

#define NPTS   40000
#define NG     4
#define NK     64
#define ND     400
#define NQ     100          // float4-quads per row (ND/4)
#define PT     128          // points per assign tile
#define NCHUNK 25           // ND / 16 (one 16x16x16 K-step per chunk)
#define NTILES 313          // ceil(NPTS / PT)
#define NSPL   16           // gather splits per cluster

typedef _Float16 f16x4 __attribute__((ext_vector_type(4)));
typedef float    f32x4 __attribute__((ext_vector_type(4)));

struct __align__(16) HL { f16x4 hi; f16x4 lo; };   // one quad: 4 dims, 2-way split

__device__ __forceinline__ HL split4(float4 v) {
    float s0 = v.x * 64.0f, s1 = v.y * 64.0f, s2 = v.z * 64.0f, s3 = v.w * 64.0f;
    _Float16 a0 = (_Float16)s0, a1 = (_Float16)s1, a2 = (_Float16)s2, a3 = (_Float16)s3;
    HL h;
    h.hi = f16x4{a0, a1, a2, a3};
    h.lo = f16x4{(_Float16)(s0 - (float)a0), (_Float16)(s1 - (float)a1),
                 (_Float16)(s2 - (float)a2), (_Float16)(s3 - (float)a3)};
    return h;
}

// ---------------------------------------------------------------------------
// One-time: patches -> f16 hi/lo splits (x64 scale). Same expression as the
// old in-kernel conversion -> downstream scores bit-identical. Pure stream:
// flat float4 index == flat HL index.
// ---------------------------------------------------------------------------
__global__ __launch_bounds__(256)
void prepass_kernel(const float* __restrict__ patches, HL* __restrict__ ps)
{
    const int total = NPTS * NG * NQ;   // 16M quads
    for (int i = blockIdx.x * 256 + threadIdx.x; i < total; i += gridDim.x * 256)
        ps[i] = split4(((const float4*)patches)[i]);
}

// ---------------------------------------------------------------------------
// e0 prep: centroid splits from cinit + zero all 10 epoch-slices of gcnt.
// ---------------------------------------------------------------------------
__global__ __launch_bounds__(128)
void centprep_kernel(const float* __restrict__ cent, HL* __restrict__ cs,
                     int* __restrict__ gcntbuf)
{
    const int gk = blockIdx.x, t = threadIdx.x;     // 256 blocks
    if (t < NQ) cs[gk * NQ + t] = split4(((const float4*)cent)[gk * NQ + t]);
    if (gk < 20 && t < 128) gcntbuf[gk * 128 + t] = 0;   // 2560 ints
}

// ---------------------------------------------------------------------------
// Assign: scores GEMM on matrix pipe (split-f16, math identical to verified
// round-1/3), argmax -> lr = (global_rank<<6)|label. Global rank via
// per-epoch cursor gcnt (also the cluster counts). Staging is now pure copy:
// uint4 split loads -> ds_write_b64 (conversion VALU deleted).
// ---------------------------------------------------------------------------
__global__ __launch_bounds__(256)
void assign_kernel(const HL* __restrict__ ps,        // [NPTS][NG][NQ]
                   const float* __restrict__ cent,   // [NG][NK][ND] fp32 (c2)
                   const HL* __restrict__ cs,        // [NG][NK][NQ]
                   int*   __restrict__ lr,           // [NG][NPTS] packed
                   int*   __restrict__ gcnt)         // [NG][NK] epoch cursor
{
    const int g    = blockIdx.y;
    const int tile = blockIdx.x;
    const int t    = threadIdx.x;
    const int n0   = tile * PT;

    __shared__ _Float16 A1[PT][20];
    __shared__ _Float16 A2[PT][20];
    __shared__ _Float16 B1[NK][20];
    __shared__ _Float16 B2[NK][20];
    __shared__ float c2p[NK][4];
    __shared__ float c2s[NK];         // 0.5*||c||^2 * 4096 (matches scaled GEMM)

    {   // half squared norms (fp32, exact), scaled by 4096
        int k = t >> 2, j = t & 3;
        const float* c = cent + ((size_t)g * NK + k) * ND + 100 * j;
        float s = 0.0f;
        #pragma unroll
        for (int d = 0; d < 100; d += 4) {
            float4 v = *(const float4*)(c + d);
            s = fmaf(v.x, v.x, fmaf(v.y, v.y, fmaf(v.z, v.z, fmaf(v.w, v.w, s))));
        }
        c2p[k][j] = s;
    }
    __syncthreads();
    if (t < NK) c2s[t] = 2048.0f * (c2p[t][0] + c2p[t][1] + c2p[t][2] + c2p[t][3]);

    const int w   = t >> 6;      // wave 0..3 -> point rows [32w, 32w+32)
    const int l   = t & 63;
    const int q   = l >> 4;      // k-quad within MFMA operand
    const int r15 = l & 15;

    // staging sources: thread t owns row (t&127), dim-half (t>>7)
    const int rh = t & 127;
    const int hh = t >> 7;
    int nn = n0 + rh; if (nn >= NPTS) nn = NPTS - 1;
    const HL* prow = ps + ((size_t)nn * NG + g) * NQ;     // +quad index
    const HL* crow = cs + ((size_t)g * NK + (t >> 2)) * NQ;
    const int jj = t & 3;

    f32x4 acc[2][4];
    {
        f32x4 z = {0.f, 0.f, 0.f, 0.f};
        #pragma unroll
        for (int i = 0; i < 2; ++i)
            #pragma unroll
            for (int j = 0; j < 4; ++j) acc[i][j] = z;
    }

    HL ha0 = prow[2 * hh];
    HL ha1 = prow[2 * hh + 1];
    HL hb  = crow[jj];

    for (int c = 0; c < NCHUNK; ++c) {
        // ---- stage current chunk (pure copy, no conversion) ----
        *(f16x4*)&A1[rh][8 * hh]     = ha0.hi;
        *(f16x4*)&A2[rh][8 * hh]     = ha0.lo;
        *(f16x4*)&A1[rh][8 * hh + 4] = ha1.hi;
        *(f16x4*)&A2[rh][8 * hh + 4] = ha1.lo;
        {
            int cc = t >> 2;
            *(f16x4*)&B1[cc][4 * jj] = hb.hi;
            *(f16x4*)&B2[cc][4 * jj] = hb.lo;
        }
        __syncthreads();

        // ---- prefetch next chunk while matrix pipe works ----
        if (c + 1 < NCHUNK) {
            const int q0 = 4 * (c + 1);
            ha0 = prow[q0 + 2 * hh];
            ha1 = prow[q0 + 2 * hh + 1];
            hb  = crow[q0 + jj];
        }

        // ---- fragments + 3-product MFMA ----
        f16x4 a1v[2], a2v[2], b1v[4], b2v[4];
        #pragma unroll
        for (int pi = 0; pi < 2; ++pi) {
            int p = 32 * w + 16 * pi + r15;          // A row = lane%16
            a1v[pi] = *(const f16x4*)&A1[p][4 * q];  // k = 4*(lane/16)+i
            a2v[pi] = *(const f16x4*)&A2[p][4 * q];
        }
        #pragma unroll
        for (int cj = 0; cj < 4; ++cj) {
            int n = 16 * cj + r15;                   // B col = lane%16
            b1v[cj] = *(const f16x4*)&B1[n][4 * q];
            b2v[cj] = *(const f16x4*)&B2[n][4 * q];
        }
        #pragma unroll
        for (int pi = 0; pi < 2; ++pi)
            #pragma unroll
            for (int cj = 0; cj < 4; ++cj) {
                acc[pi][cj] = __builtin_amdgcn_mfma_f32_16x16x16f16(a2v[pi], b1v[cj], acc[pi][cj], 0, 0, 0);
                acc[pi][cj] = __builtin_amdgcn_mfma_f32_16x16x16f16(a1v[pi], b2v[cj], acc[pi][cj], 0, 0, 0);
                acc[pi][cj] = __builtin_amdgcn_mfma_f32_16x16x16f16(a1v[pi], b1v[cj], acc[pi][cj], 0, 0, 0);
            }
        __syncthreads();
    }

    // ---- argmax epilogue (ties -> lowest cluster, matches jnp.argmax) ----
    #pragma unroll
    for (int pi = 0; pi < 2; ++pi) {
        #pragma unroll
        for (int r = 0; r < 4; ++r) {
            float m  = acc[pi][0][r] - c2s[r15];
            int best = r15;
            #pragma unroll
            for (int cj = 1; cj < 4; ++cj) {
                int n = 16 * cj + r15;
                float s = acc[pi][cj][r] - c2s[n];
                if (s > m) { m = s; best = n; }
            }
            #pragma unroll
            for (int off = 1; off < 16; off <<= 1) {
                float om = __shfl_xor(m, off);
                int   ob = __shfl_xor(best, off);
                if (om > m || (om == m && ob < best)) { m = om; best = ob; }
            }
            if (r15 == 0) {
                int p  = 32 * w + 16 * pi + 4 * q + r;
                int np = n0 + p;
                if (np < NPTS) {
                    int rk = atomicAdd(&gcnt[g * NK + best], 1);  // global rank
                    lr[(size_t)g * NPTS + np] = (rk << 6) | best;
                }
            }
        }
    }
}

// ---------------------------------------------------------------------------
// Scatter: order[g][kbase[L] + global_rank] = n. kbase = 64-int prefix of
// gcnt, computed locally (no scan kernel, no tilebase array).
// ---------------------------------------------------------------------------
__global__ __launch_bounds__(128)
void scatter_kernel(const int* __restrict__ lr,     // [NG][NPTS]
                    const int* __restrict__ gcnt,   // [NG][NK]
                    int* __restrict__ order)        // [NG][NPTS]
{
    const int tile = blockIdx.x, g = blockIdx.y, t = threadIdx.x;
    __shared__ int kb[NK];
    if (t == 0) {
        int run = 0;
        for (int k = 0; k < NK; ++k) { kb[k] = run; run += gcnt[g * NK + k]; }
    }
    __syncthreads();
    const int n = tile * PT + t;
    if (n < NPTS) {
        int packed = lr[(size_t)g * NPTS + n];
        int L = packed & 63, r = packed >> 6;
        order[(size_t)g * NPTS + kb[L] + r] = n;
    }
}

// ---------------------------------------------------------------------------
// Gather: block = (split, k, g). 5 points x 100 lanes, register acc over the
// split rows (hi+lo fp32 reconstruction, x64 scale). base/cnt derived from
// gcnt prefix locally.
// ---------------------------------------------------------------------------
__global__ __launch_bounds__(512, 2)
void gather_kernel(const HL*  __restrict__ ps,      // [NPTS][NG][NQ]
                   const int* __restrict__ order,   // [NG][NPTS]
                   const int* __restrict__ gcnt,    // [NG][NK]
                   float* __restrict__ psum)        // [NG][NK][NSPL][ND] (x64)
{
    const int s = blockIdx.x, k = blockIdx.y, g = blockIdx.z;
    const int t = threadIdx.x;

    __shared__ int sb[2];
    if (t == 0) {
        int b = 0;
        for (int i = 0; i < k; ++i) b += gcnt[g * NK + i];
        sb[0] = b; sb[1] = gcnt[g * NK + k];
    }
    __syncthreads();
    const int base = sb[0], cnt = sb[1];
    const int start = base + (cnt * s) / NSPL;
    const int end   = base + (cnt * (s + 1)) / NSPL;

    const int slot = t / 100;          // 0..4 active (t<500)
    const int q    = t - slot * 100;   // d-quad 0..99

    float4 acc = make_float4(0.f, 0.f, 0.f, 0.f);
    if (t < 500) {
        const int* ord = order + (size_t)g * NPTS;
        #pragma unroll 2
        for (int i = start + slot; i < end; i += 5) {
            int n = ord[i];
            HL h = ps[((size_t)n * NG + g) * NQ + q];
            acc.x += (float)h.hi[0] + (float)h.lo[0];
            acc.y += (float)h.hi[1] + (float)h.lo[1];
            acc.z += (float)h.hi[2] + (float)h.lo[2];
            acc.w += (float)h.hi[3] + (float)h.lo[3];
        }
    }

    __shared__ float sums[ND];
    for (int i = t; i < ND; i += 512) sums[i] = 0.0f;
    __syncthreads();
    if (t < 500) {
        atomicAdd(&sums[4 * q + 0], acc.x);
        atomicAdd(&sums[4 * q + 1], acc.y);
        atomicAdd(&sums[4 * q + 2], acc.z);
        atomicAdd(&sums[4 * q + 3], acc.w);
    }
    __syncthreads();
    if (t < 100) {
        float* dst = psum + (((size_t)(g * NK + k)) * NSPL + s) * ND + 4 * t;
        *(float4*)dst = *(const float4*)&sums[4 * t];
    }
}

// ---------------------------------------------------------------------------
// Update: reduce NSPL partials (x64-scaled), divide (+1/64 descale), apply
// empty-in-any-group zeroing, write fp32 centroids AND their f16 splits for
// the next assign.
// ---------------------------------------------------------------------------
__global__ __launch_bounds__(128)
void update_kernel(const float* __restrict__ psum,   // [NG][NK][NSPL][ND]
                   const int*   __restrict__ gcnt,   // [NG][NK]
                   float* __restrict__ outc,         // [NG][NK][ND]
                   HL*    __restrict__ cs)           // [NG][NK][NQ]
{
    const int gk = blockIdx.x;
    const int g = gk >> 6, k = gk & 63;
    const int t = threadIdx.x;

    const bool bad = (gcnt[0 * NK + k] == 0) | (gcnt[1 * NK + k] == 0) |
                     (gcnt[2 * NK + k] == 0) | (gcnt[3 * NK + k] == 0);
    const int  c  = gcnt[g * NK + k];
    const float inv = 1.0f / (float)(c == 0 ? 1 : c);

    if (t < NQ) {
        float4 s = make_float4(0.f, 0.f, 0.f, 0.f);
        const float* p = psum + ((size_t)gk * NSPL) * ND + 4 * t;
        #pragma unroll
        for (int sp = 0; sp < NSPL; ++sp) {
            float4 v = *(const float4*)(p + (size_t)sp * ND);
            s.x += v.x; s.y += v.y; s.z += v.z; s.w += v.w;
        }
        // c64 = 64 * centroid (exactly the split input scale)
        float4 c64;
        c64.x = bad ? 0.0f : s.x * inv;
        c64.y = bad ? 0.0f : s.y * inv;
        c64.z = bad ? 0.0f : s.z * inv;
        c64.w = bad ? 0.0f : s.w * inv;
        float4 o = make_float4(c64.x * 0.015625f, c64.y * 0.015625f,
                               c64.z * 0.015625f, c64.w * 0.015625f);
        *(float4*)(outc + (size_t)gk * ND + 4 * t) = o;
        // emit splits directly from c64 (== split4(o): same expression)
        _Float16 a0 = (_Float16)c64.x, a1 = (_Float16)c64.y,
                 a2 = (_Float16)c64.z, a3 = (_Float16)c64.w;
        HL h;
        h.hi = f16x4{a0, a1, a2, a3};
        h.lo = f16x4{(_Float16)(c64.x - (float)a0), (_Float16)(c64.y - (float)a1),
                     (_Float16)(c64.z - (float)a2), (_Float16)(c64.w - (float)a3)};
        cs[(size_t)gk * NQ + t] = h;
    }
}

extern "C" void kernel_launch(void* const* d_in, const int* in_sizes, int n_in,
                              void* d_out, int out_size, void* d_ws, size_t ws_size,
                              hipStream_t stream)
{
    const float* patches = (const float*)d_in[0];
    const float* cinit   = (const float*)d_in[1];
    float* out = (float*)d_out;

    char* wp = (char*)d_ws;
    HL* PS = (HL*)wp;               wp += (size_t)NPTS * NG * NQ * sizeof(HL);  // 256 MB
    HL* CS = (HL*)wp;               wp += (size_t)NG * NK * NQ * sizeof(HL);    // 400 KB
    float* centA = (float*)wp;      wp += (size_t)NG * NK * ND * 4;
    float* centB = (float*)wp;      wp += (size_t)NG * NK * ND * 4;
    int* lr      = (int*)wp;        wp += (size_t)NG * NPTS * 4;
    int* order   = (int*)wp;        wp += (size_t)NG * NPTS * 4;
    int* gcntbuf = (int*)wp;        wp += 2560 * 4;                              // 10 epochs x 256
    float* psum  = (float*)wp;      // NG*NK*NSPL*ND floats = 26.2 MB

    prepass_kernel<<<4096, 256, 0, stream>>>(patches, PS);
    centprep_kernel<<<NG * NK, 128, 0, stream>>>(cinit, CS, gcntbuf);

    const float* cur = cinit;
    for (int e = 0; e < 10; ++e) {
        int* gc = gcntbuf + 256 * e;
        assign_kernel<<<dim3(NTILES, NG), 256, 0, stream>>>(PS, cur, CS, lr, gc);
        scatter_kernel<<<dim3(NTILES, NG), 128, 0, stream>>>(lr, gc, order);
        gather_kernel<<<dim3(NSPL, NK, NG), 512, 0, stream>>>(PS, order, gc, psum);
        float* nxt = (e == 9) ? out : ((e & 1) ? centB : centA);
        update_kernel<<<NG * NK, 128, 0, stream>>>(psum, gc, nxt, CS);
        cur = nxt;
    }
}

// Round 5
// 1663.176 us; speedup vs baseline: 2.5837x; 2.5837x over previous
//
#include <hip/hip_runtime.h>

#define NPTS   40000
#define NG     4
#define NK     64
#define ND     400
#define NQ     100          // float4-quads per row (ND/4)
#define PT     128          // points per assign tile
#define NCHUNK 25           // ND / 16 (one 16x16x16 K-step per chunk)
#define NTILES 313          // ceil(NPTS / PT)
#define NSPL   16           // gather splits per cluster

typedef _Float16 f16x4 __attribute__((ext_vector_type(4)));
typedef float    f32x4 __attribute__((ext_vector_type(4)));

struct __align__(16) HL { f16x4 hi; f16x4 lo; };   // one quad: 4 dims, 2-way split

__device__ __forceinline__ HL split4(float4 v) {
    float s0 = v.x * 64.0f, s1 = v.y * 64.0f, s2 = v.z * 64.0f, s3 = v.w * 64.0f;
    _Float16 a0 = (_Float16)s0, a1 = (_Float16)s1, a2 = (_Float16)s2, a3 = (_Float16)s3;
    HL h;
    h.hi = f16x4{a0, a1, a2, a3};
    h.lo = f16x4{(_Float16)(s0 - (float)a0), (_Float16)(s1 - (float)a1),
                 (_Float16)(s2 - (float)a2), (_Float16)(s3 - (float)a3)};
    return h;
}

// ---------------------------------------------------------------------------
// One-time: patches [n][g][q] -> f16 hi/lo splits PS [g][n][q] (x64 scale).
// Same split expression as always -> downstream scores bit-identical.
// ---------------------------------------------------------------------------
__global__ __launch_bounds__(256)
void prepass_kernel(const float* __restrict__ patches, HL* __restrict__ ps)
{
    const int total = NPTS * NG * NQ;   // 16M quads
    for (int i = blockIdx.x * 256 + threadIdx.x; i < total; i += gridDim.x * 256) {
        int n = i / (NG * NQ);
        int r = i - n * (NG * NQ);
        int g = r / NQ, q = r - g * NQ;
        ps[((size_t)g * NPTS + n) * NQ + q] = split4(((const float4*)patches)[i]);
    }
}

// ---------------------------------------------------------------------------
// e0 prep: centroid splits + c2 (0.5*||c||^2 * 4096) from cinit.
// c2 chain replicates round-3's exact fmaf order (4 chunks of 100, nested).
// ---------------------------------------------------------------------------
__global__ __launch_bounds__(128)
void centprep_kernel(const float* __restrict__ cent, HL* __restrict__ cs,
                     float* __restrict__ c2g)
{
    const int gk = blockIdx.x, t = threadIdx.x;     // 256 blocks
    __shared__ float p4[4];
    if (t < NQ) cs[(size_t)gk * NQ + t] = split4(((const float4*)cent)[gk * NQ + t]);
    if (t >= 100 && t < 104) {
        int j = t - 100;
        const float* c = cent + (size_t)gk * ND + 100 * j;
        float s = 0.0f;
        #pragma unroll
        for (int d = 0; d < 100; d += 4) {
            float4 v = *(const float4*)(c + d);
            s = fmaf(v.x, v.x, fmaf(v.y, v.y, fmaf(v.z, v.z, fmaf(v.w, v.w, s))));
        }
        p4[j] = s;
    }
    __syncthreads();
    if (t == 0) c2g[gk] = 2048.0f * (p4[0] + p4[1] + p4[2] + p4[3]);
}

// ---------------------------------------------------------------------------
// Assign: scores GEMM on matrix pipe (split-f16, math bit-identical to the
// verified round-3 kernel), argmax -> lr=(tile_rank<<8)|label + pcnt.
// Staging is pure 16B copy from PS/CS (no conversion VALU, no c2 prologue).
// Double-buffered LDS: ONE barrier per chunk instead of two.
// ---------------------------------------------------------------------------
__global__ __launch_bounds__(256)
void assign_kernel(const HL* __restrict__ ps,        // [NG][NPTS][NQ]
                   const HL* __restrict__ cs,        // [NG][NK][NQ]
                   const float* __restrict__ c2g,    // [NG][NK]
                   int*   __restrict__ lr,           // [NG][NPTS] packed
                   int*   __restrict__ pcnt)         // [NG][NTILES][NK]
{
    const int g    = blockIdx.y;
    const int tile = blockIdx.x;
    const int t    = threadIdx.x;
    const int n0   = tile * PT;

    __shared__ _Float16 A1[2][PT][20];
    __shared__ _Float16 A2[2][PT][20];
    __shared__ _Float16 B1[2][NK][20];
    __shared__ _Float16 B2[2][NK][20];
    __shared__ float c2s[NK];
    __shared__ int   cnt[NK];

    if (t < NK) { c2s[t] = c2g[g * NK + t]; cnt[t] = 0; }

    const int w   = t >> 6;      // wave 0..3 -> point rows [32w, 32w+32)
    const int l   = t & 63;
    const int q   = l >> 4;      // k-quad within MFMA operand
    const int r15 = l & 15;

    // staging sources: thread t owns row (t&127), dim-half (t>>7)
    const int rh = t & 127;
    const int hh = t >> 7;
    int nn = n0 + rh; if (nn >= NPTS) nn = NPTS - 1;
    const HL* prow = ps + ((size_t)g * NPTS + nn) * NQ;
    const HL* crow = cs + ((size_t)g * NK + (t >> 2)) * NQ;
    const int jj = t & 3;
    const int cc = t >> 2;

    f32x4 acc[2][4];
    {
        f32x4 z = {0.f, 0.f, 0.f, 0.f};
        #pragma unroll
        for (int i = 0; i < 2; ++i)
            #pragma unroll
            for (int j = 0; j < 4; ++j) acc[i][j] = z;
    }

    // chunk 0 -> regs -> buf 0
    HL ha0 = prow[2 * hh];
    HL ha1 = prow[2 * hh + 1];
    HL hb  = crow[jj];
    *(f16x4*)&A1[0][rh][8 * hh]     = ha0.hi;
    *(f16x4*)&A2[0][rh][8 * hh]     = ha0.lo;
    *(f16x4*)&A1[0][rh][8 * hh + 4] = ha1.hi;
    *(f16x4*)&A2[0][rh][8 * hh + 4] = ha1.lo;
    *(f16x4*)&B1[0][cc][4 * jj]     = hb.hi;
    *(f16x4*)&B2[0][cc][4 * jj]     = hb.lo;
    __syncthreads();
    // prefetch chunk 1
    ha0 = prow[4 + 2 * hh];
    ha1 = prow[4 + 2 * hh + 1];
    hb  = crow[4 + jj];

    for (int c = 0; c < NCHUNK; ++c) {
        const int cur = c & 1;

        // ---- fragments + 3-product MFMA from buf[cur] ----
        f16x4 a1v[2], a2v[2], b1v[4], b2v[4];
        #pragma unroll
        for (int pi = 0; pi < 2; ++pi) {
            int p = 32 * w + 16 * pi + r15;               // A row = lane%16
            a1v[pi] = *(const f16x4*)&A1[cur][p][4 * q];  // k = 4*(lane/16)+i
            a2v[pi] = *(const f16x4*)&A2[cur][p][4 * q];
        }
        #pragma unroll
        for (int cj = 0; cj < 4; ++cj) {
            int n = 16 * cj + r15;                        // B col = lane%16
            b1v[cj] = *(const f16x4*)&B1[cur][n][4 * q];
            b2v[cj] = *(const f16x4*)&B2[cur][n][4 * q];
        }
        #pragma unroll
        for (int pi = 0; pi < 2; ++pi)
            #pragma unroll
            for (int cj = 0; cj < 4; ++cj) {
                acc[pi][cj] = __builtin_amdgcn_mfma_f32_16x16x16f16(a2v[pi], b1v[cj], acc[pi][cj], 0, 0, 0);
                acc[pi][cj] = __builtin_amdgcn_mfma_f32_16x16x16f16(a1v[pi], b2v[cj], acc[pi][cj], 0, 0, 0);
                acc[pi][cj] = __builtin_amdgcn_mfma_f32_16x16x16f16(a1v[pi], b1v[cj], acc[pi][cj], 0, 0, 0);
            }

        // ---- write prefetched chunk c+1 into the other buffer ----
        if (c + 1 < NCHUNK) {
            const int nxt = cur ^ 1;
            *(f16x4*)&A1[nxt][rh][8 * hh]     = ha0.hi;
            *(f16x4*)&A2[nxt][rh][8 * hh]     = ha0.lo;
            *(f16x4*)&A1[nxt][rh][8 * hh + 4] = ha1.hi;
            *(f16x4*)&A2[nxt][rh][8 * hh + 4] = ha1.lo;
            *(f16x4*)&B1[nxt][cc][4 * jj]     = hb.hi;
            *(f16x4*)&B2[nxt][cc][4 * jj]     = hb.lo;
        }
        __syncthreads();
        // ---- prefetch chunk c+2 ----
        if (c + 2 < NCHUNK) {
            const int q0 = 4 * (c + 2);
            ha0 = prow[q0 + 2 * hh];
            ha1 = prow[q0 + 2 * hh + 1];
            hb  = crow[q0 + jj];
        }
    }

    // ---- argmax epilogue (ties -> lowest cluster, matches jnp.argmax) ----
    #pragma unroll
    for (int pi = 0; pi < 2; ++pi) {
        #pragma unroll
        for (int r = 0; r < 4; ++r) {
            float m  = acc[pi][0][r] - c2s[r15];
            int best = r15;
            #pragma unroll
            for (int cj = 1; cj < 4; ++cj) {
                int n = 16 * cj + r15;
                float s = acc[pi][cj][r] - c2s[n];
                if (s > m) { m = s; best = n; }
            }
            #pragma unroll
            for (int off = 1; off < 16; off <<= 1) {
                float om = __shfl_xor(m, off);
                int   ob = __shfl_xor(best, off);
                if (om > m || (om == m && ob < best)) { m = om; best = ob; }
            }
            if (r15 == 0) {
                int p  = 32 * w + 16 * pi + 4 * q + r;
                int np = n0 + p;
                if (np < NPTS) {
                    int rk = atomicAdd(&cnt[best], 1);   // LDS int rank (fast)
                    lr[(size_t)g * NPTS + np] = (rk << 8) | best;
                }
            }
        }
    }
    __syncthreads();
    if (t < NK) pcnt[((size_t)g * NTILES + tile) * NK + t] = cnt[t];
}

// ---------------------------------------------------------------------------
// Fused scan+scatter (round-3 proven): each block stages pcnt[g] (u16),
// computes cluster totals, cbase, own-tile prefix, then scatters.
// ---------------------------------------------------------------------------
__global__ __launch_bounds__(256)
void scatter2_kernel(const int* __restrict__ lr,     // [NG][NPTS]
                     const int* __restrict__ pcnt,   // [NG][NTILES][NK]
                     int* __restrict__ order,        // [NG][NPTS]
                     int* __restrict__ cbase,        // [NG][NK]
                     int* __restrict__ counts)       // [NG][NK]
{
    const int tile = blockIdx.x, g = blockIdx.y, t = threadIdx.x;
    __shared__ unsigned short cnt_tk[NTILES * NK];   // 40064 B (counts <= 128)
    __shared__ int part [4][NK];
    __shared__ int part2[4][NK];
    __shared__ int kbase[NK];
    __shared__ int tpre[NK];

    const int* pg = pcnt + (size_t)g * NTILES * NK;
    for (int i = t; i < NTILES * NK; i += 256)
        cnt_tk[i] = (unsigned short)pg[i];
    __syncthreads();

    {   // 4-way split sums: totals and own-tile prefix per k
        int k = t & 63, p = t >> 6;
        int s1 = 0, s2 = 0;
        for (int tl = p; tl < NTILES; tl += 4) {
            int v = cnt_tk[tl * NK + k];
            s1 += v;
            if (tl < tile) s2 += v;
        }
        part [p][k] = s1;
        part2[p][k] = s2;
    }
    __syncthreads();
    if (t < NK) {
        part[0][t] = part[0][t] + part[1][t] + part[2][t] + part[3][t];   // totals
        tpre[t]    = part2[0][t] + part2[1][t] + part2[2][t] + part2[3][t];
    }
    __syncthreads();
    if (t == 0) {
        int run = 0;
        for (int k = 0; k < NK; ++k) { kbase[k] = run; run += part[0][k]; }
    }
    __syncthreads();
    if (tile == 0 && t < NK) {
        cbase[g * NK + t]  = kbase[t];
        counts[g * NK + t] = part[0][t];
    }
    const int n = tile * PT + t;
    if (t < PT && n < NPTS) {
        int packed = lr[(size_t)g * NPTS + n];
        int L = packed & 63, r = packed >> 8;
        order[(size_t)g * NPTS + kbase[L] + tpre[L] + r] = n;
    }
}

// ---------------------------------------------------------------------------
// Gather: block = (split, k, g). 5 points x 100 lanes, register acc over
// split rows (hi+lo, x64 scale). Finish via 5 disjoint partial rows + tree
// add — NO fp32 LDS atomics (they are CAS loops; round-2 lesson).
// ---------------------------------------------------------------------------
__global__ __launch_bounds__(512, 2)
void gather_kernel(const HL*  __restrict__ ps,      // [NG][NPTS][NQ]
                   const int* __restrict__ order,   // [NG][NPTS]
                   const int* __restrict__ cbase,   // [NG][NK]
                   const int* __restrict__ counts,  // [NG][NK]
                   float* __restrict__ psum)        // [NG][NK][NSPL][ND] (x64)
{
    const int s = blockIdx.x, k = blockIdx.y, g = blockIdx.z;
    const int t = threadIdx.x;
    const int base = cbase[g * NK + k];
    const int cnt  = counts[g * NK + k];
    const int start = base + (cnt * s) / NSPL;
    const int end   = base + (cnt * (s + 1)) / NSPL;

    const int slot = t / 100;          // 0..4 active (t<500)
    const int q    = t - slot * 100;   // d-quad 0..99

    __shared__ float sums[5][ND];      // 8 KB, disjoint per slot

    float4 acc = make_float4(0.f, 0.f, 0.f, 0.f);
    if (t < 500) {
        const int* ord = order + (size_t)g * NPTS;
        #pragma unroll 2
        for (int i = start + slot; i < end; i += 5) {
            int n = ord[i];
            HL h = ps[((size_t)g * NPTS + n) * NQ + q];
            acc.x += (float)h.hi[0] + (float)h.lo[0];
            acc.y += (float)h.hi[1] + (float)h.lo[1];
            acc.z += (float)h.hi[2] + (float)h.lo[2];
            acc.w += (float)h.hi[3] + (float)h.lo[3];
        }
        *(float4*)&sums[slot][4 * q] = acc;
    }
    __syncthreads();
    if (t < NQ) {
        float4 a0 = *(const float4*)&sums[0][4 * t];
        float4 a1 = *(const float4*)&sums[1][4 * t];
        float4 a2 = *(const float4*)&sums[2][4 * t];
        float4 a3 = *(const float4*)&sums[3][4 * t];
        float4 a4 = *(const float4*)&sums[4][4 * t];
        float4 o;
        o.x = a0.x + a1.x + a2.x + a3.x + a4.x;
        o.y = a0.y + a1.y + a2.y + a3.y + a4.y;
        o.z = a0.z + a1.z + a2.z + a3.z + a4.z;
        o.w = a0.w + a1.w + a2.w + a3.w + a4.w;
        float* dst = psum + (((size_t)(g * NK + k)) * NSPL + s) * ND + 4 * t;
        *(float4*)dst = o;
    }
}

// ---------------------------------------------------------------------------
// Update: reduce NSPL partials (x64 scale), divide, descale (x2^-6 exact),
// empty-in-any-group zeroing; emit fp32 centroids + f16 splits + c2 for the
// next epoch's assign.
// ---------------------------------------------------------------------------
__global__ __launch_bounds__(128)
void update_kernel(const float* __restrict__ psum,   // [NG][NK][NSPL][ND]
                   const int*   __restrict__ counts, // [NG][NK]
                   float* __restrict__ outc,         // [NG][NK][ND]
                   HL*    __restrict__ cs,           // [NG][NK][NQ]
                   float* __restrict__ c2g)          // [NG][NK]
{
    const int gk = blockIdx.x;
    const int g = gk >> 6, k = gk & 63;
    const int t = threadIdx.x;

    __shared__ float qp[NQ];
    __shared__ float p4[4];

    const bool bad = (counts[0 * NK + k] == 0) | (counts[1 * NK + k] == 0) |
                     (counts[2 * NK + k] == 0) | (counts[3 * NK + k] == 0);
    const int  c  = counts[g * NK + k];
    const float inv = 1.0f / (float)(c == 0 ? 1 : c);

    if (t < NQ) {
        float4 s = make_float4(0.f, 0.f, 0.f, 0.f);
        const float* p = psum + ((size_t)gk * NSPL) * ND + 4 * t;
        #pragma unroll
        for (int sp = 0; sp < NSPL; ++sp) {
            float4 v = *(const float4*)(p + (size_t)sp * ND);
            s.x += v.x; s.y += v.y; s.z += v.z; s.w += v.w;
        }
        float4 c64;   // 64 * centroid (exactly the split input scale)
        c64.x = bad ? 0.0f : s.x * inv;
        c64.y = bad ? 0.0f : s.y * inv;
        c64.z = bad ? 0.0f : s.z * inv;
        c64.w = bad ? 0.0f : s.w * inv;
        float4 o = make_float4(c64.x * 0.015625f, c64.y * 0.015625f,
                               c64.z * 0.015625f, c64.w * 0.015625f);
        *(float4*)(outc + (size_t)gk * ND + 4 * t) = o;
        // splits from c64 (same expression as split4(o), since o*64 == c64)
        _Float16 a0 = (_Float16)c64.x, a1 = (_Float16)c64.y,
                 a2 = (_Float16)c64.z, a3 = (_Float16)c64.w;
        HL h;
        h.hi = f16x4{a0, a1, a2, a3};
        h.lo = f16x4{(_Float16)(c64.x - (float)a0), (_Float16)(c64.y - (float)a1),
                     (_Float16)(c64.z - (float)a2), (_Float16)(c64.w - (float)a3)};
        cs[(size_t)gk * NQ + t] = h;
        // per-quad squared-norm partial (nested fmaf like round-3's inner chain)
        qp[t] = fmaf(o.x, o.x, fmaf(o.y, o.y, fmaf(o.z, o.z, o.w * o.w)));
    }
    __syncthreads();
    if (t < 4) {
        float s = 0.0f;
        for (int i = 25 * t; i < 25 * t + 25; ++i) s += qp[i];
        p4[t] = s;
    }
    __syncthreads();
    if (t == 0) c2g[gk] = 2048.0f * (((p4[0] + p4[1]) + p4[2]) + p4[3]);
}

extern "C" void kernel_launch(void* const* d_in, const int* in_sizes, int n_in,
                              void* d_out, int out_size, void* d_ws, size_t ws_size,
                              hipStream_t stream)
{
    const float* patches = (const float*)d_in[0];
    const float* cinit   = (const float*)d_in[1];
    float* out = (float*)d_out;

    char* wp = (char*)d_ws;
    HL* PS = (HL*)wp;               wp += (size_t)NPTS * NG * NQ * sizeof(HL);  // 256 MB
    HL* CS = (HL*)wp;               wp += (size_t)NG * NK * NQ * sizeof(HL);    // 400 KB
    float* c2g = (float*)wp;        wp += (size_t)NG * NK * 4;
    float* centA = (float*)wp;      wp += (size_t)NG * NK * ND * 4;
    float* centB = (float*)wp;      wp += (size_t)NG * NK * ND * 4;
    int* lr      = (int*)wp;        wp += (size_t)NG * NPTS * 4;
    int* order   = (int*)wp;        wp += (size_t)NG * NPTS * 4;
    int* pcnt    = (int*)wp;        wp += (size_t)NG * NTILES * NK * 4;
    int* cbase   = (int*)wp;        wp += (size_t)NG * NK * 4;
    int* counts  = (int*)wp;        wp += (size_t)NG * NK * 4;
    float* psum  = (float*)wp;      // NG*NK*NSPL*ND floats = 26.2 MB

    prepass_kernel<<<4096, 256, 0, stream>>>(patches, PS);
    centprep_kernel<<<NG * NK, 128, 0, stream>>>(cinit, CS, c2g);

    const float* cur = cinit;
    for (int e = 0; e < 10; ++e) {
        assign_kernel<<<dim3(NTILES, NG), 256, 0, stream>>>(PS, CS, c2g, lr, pcnt);
        scatter2_kernel<<<dim3(NTILES, NG), 256, 0, stream>>>(lr, pcnt, order, cbase, counts);
        gather_kernel<<<dim3(NSPL, NK, NG), 512, 0, stream>>>(PS, order, cbase, counts, psum);
        float* nxt = (e == 9) ? out : ((e & 1) ? centB : centA);
        update_kernel<<<NG * NK, 128, 0, stream>>>(psum, counts, nxt, CS, c2g);
        cur = nxt;
    }
    (void)cur;
}

// Round 6
// 1652.282 us; speedup vs baseline: 2.6007x; 1.0066x over previous
//
#include <hip/hip_runtime.h>

#define NPTS   40000
#define NG     4
#define NK     64
#define ND     400
#define NQ     100          // float4-quads per row (ND/4)
#define PT     128          // points per assign tile
#define NCHUNK 13           // ceil(ND/32) 32-dim K-chunks (last half zero-pad)
#define NTILES 313          // ceil(NPTS / PT)
#define NSPL   16           // gather splits per cluster
#define LSTR   36           // LDS row stride in f16 (72 B: 8B-aligned, word-stride 18 unit-cyclic mod 32 -> conflict floor)

typedef _Float16 f16x4 __attribute__((ext_vector_type(4)));
typedef float    f32x4 __attribute__((ext_vector_type(4)));

struct __align__(16) HL { f16x4 hi; f16x4 lo; };   // one quad: 4 dims, 2-way split

__device__ __forceinline__ HL split4(float4 v) {
    float s0 = v.x * 64.0f, s1 = v.y * 64.0f, s2 = v.z * 64.0f, s3 = v.w * 64.0f;
    _Float16 a0 = (_Float16)s0, a1 = (_Float16)s1, a2 = (_Float16)s2, a3 = (_Float16)s3;
    HL h;
    h.hi = f16x4{a0, a1, a2, a3};
    h.lo = f16x4{(_Float16)(s0 - (float)a0), (_Float16)(s1 - (float)a1),
                 (_Float16)(s2 - (float)a2), (_Float16)(s3 - (float)a3)};
    return h;
}

__device__ __forceinline__ HL hlzero() {
    HL h;
    h.hi = f16x4{(_Float16)0.f, (_Float16)0.f, (_Float16)0.f, (_Float16)0.f};
    h.lo = h.hi;
    return h;
}

// ---------------------------------------------------------------------------
// One-time: patches [n][g][q] -> f16 hi/lo splits PS [g][n][q] (x64 scale).
// ---------------------------------------------------------------------------
__global__ __launch_bounds__(256)
void prepass_kernel(const float* __restrict__ patches, HL* __restrict__ ps)
{
    const int total = NPTS * NG * NQ;   // 16M quads
    for (int i = blockIdx.x * 256 + threadIdx.x; i < total; i += gridDim.x * 256) {
        int n = i / (NG * NQ);
        int r = i - n * (NG * NQ);
        int g = r / NQ, q = r - g * NQ;
        ps[((size_t)g * NPTS + n) * NQ + q] = split4(((const float4*)patches)[i]);
    }
}

// ---------------------------------------------------------------------------
// e0 prep: centroid splits + c2 (0.5*||c||^2 * 4096) from cinit.
// ---------------------------------------------------------------------------
__global__ __launch_bounds__(128)
void centprep_kernel(const float* __restrict__ cent, HL* __restrict__ cs,
                     float* __restrict__ c2g)
{
    const int gk = blockIdx.x, t = threadIdx.x;     // 256 blocks
    __shared__ float p4[4];
    if (t < NQ) cs[(size_t)gk * NQ + t] = split4(((const float4*)cent)[gk * NQ + t]);
    if (t >= 100 && t < 104) {
        int j = t - 100;
        const float* c = cent + (size_t)gk * ND + 100 * j;
        float s = 0.0f;
        #pragma unroll
        for (int d = 0; d < 100; d += 4) {
            float4 v = *(const float4*)(c + d);
            s = fmaf(v.x, v.x, fmaf(v.y, v.y, fmaf(v.z, v.z, fmaf(v.w, v.w, s))));
        }
        p4[j] = s;
    }
    __syncthreads();
    if (t == 0) c2g[gk] = 2048.0f * (p4[0] + p4[1] + p4[2] + p4[3]);
}

// ---------------------------------------------------------------------------
// Assign: split-f16 scores GEMM on the matrix pipe. 32-dim K-chunks,
// double-buffered LDS, ONE barrier per chunk (13 total, was 25).
// Same MFMA shape/order as the verified kernel -> labels bit-identical.
// LDS rows stride-36 f16: conflict-floor for b64 reads AND writes.
// ---------------------------------------------------------------------------
__global__ __launch_bounds__(256)
void assign_kernel(const HL* __restrict__ ps,        // [NG][NPTS][NQ]
                   const HL* __restrict__ cs,        // [NG][NK][NQ]
                   const float* __restrict__ c2g,    // [NG][NK]
                   unsigned short* __restrict__ lr,  // [NG][NPTS] packed (rank<<8)|label
                   unsigned char*  __restrict__ pcnt)// [NG][NTILES][NK]
{
    const int g    = blockIdx.y;
    const int tile = blockIdx.x;
    const int t    = threadIdx.x;
    const int n0   = tile * PT;

    __shared__ _Float16 A1[2][PT][LSTR];
    __shared__ _Float16 A2[2][PT][LSTR];
    __shared__ _Float16 B1[2][NK][LSTR];
    __shared__ _Float16 B2[2][NK][LSTR];
    __shared__ float c2s[NK];
    __shared__ int   cnt[NK];

    if (t < NK) { c2s[t] = c2g[g * NK + t]; cnt[t] = 0; }

    const int w   = t >> 6;      // wave 0..3 -> point rows [32w, 32w+32)
    const int l   = t & 63;
    const int q   = l >> 4;      // k-quad within MFMA operand
    const int r15 = l & 15;

    // staging: thread t owns point row rh=t&127, dim-half hh=t>>7 (16 dims);
    // and centroid row cc=t>>2, dim-eighth jj=t&3 (8 dims).
    const int rh = t & 127;
    const int hh = t >> 7;
    int nn = n0 + rh; if (nn >= NPTS) nn = NPTS - 1;
    const HL* prow = ps + ((size_t)g * NPTS + nn) * NQ;
    const HL* crow = cs + ((size_t)g * NK + (t >> 2)) * NQ;
    const int jj = t & 3;
    const int cc = t >> 2;

    f32x4 acc[2][4];
    {
        f32x4 z = {0.f, 0.f, 0.f, 0.f};
        #pragma unroll
        for (int i = 0; i < 2; ++i)
            #pragma unroll
            for (int j = 0; j < 4; ++j) acc[i][j] = z;
    }

    HL a[4], b[2];   // one 32-dim chunk in regs: A quads 8c+4hh+m, B quads 8c+2jj+m

    // load chunk 0
    #pragma unroll
    for (int m = 0; m < 4; ++m) { int qa = 4 * hh + m; a[m] = (qa < NQ) ? prow[qa] : hlzero(); }
    #pragma unroll
    for (int m = 0; m < 2; ++m) { int qb = 2 * jj + m; b[m] = (qb < NQ) ? crow[qb] : hlzero(); }
    // stage chunk 0 -> buf 0
    #pragma unroll
    for (int m = 0; m < 4; ++m) {
        *(f16x4*)&A1[0][rh][4 * (4 * hh + m)] = a[m].hi;
        *(f16x4*)&A2[0][rh][4 * (4 * hh + m)] = a[m].lo;
    }
    #pragma unroll
    for (int m = 0; m < 2; ++m) {
        *(f16x4*)&B1[0][cc][4 * (2 * jj + m)] = b[m].hi;
        *(f16x4*)&B2[0][cc][4 * (2 * jj + m)] = b[m].lo;
    }
    __syncthreads();
    // prefetch chunk 1
    #pragma unroll
    for (int m = 0; m < 4; ++m) { int qa = 8 + 4 * hh + m; a[m] = (qa < NQ) ? prow[qa] : hlzero(); }
    #pragma unroll
    for (int m = 0; m < 2; ++m) { int qb = 8 + 2 * jj + m; b[m] = (qb < NQ) ? crow[qb] : hlzero(); }

    for (int c = 0; c < NCHUNK; ++c) {
        const int cur = c & 1;

        // ---- two 16-dim k-steps from buf[cur], same MFMA order as verified ----
        #pragma unroll
        for (int s = 0; s < 2; ++s) {
            f16x4 a1v[2], a2v[2], b1v[4], b2v[4];
            #pragma unroll
            for (int pi = 0; pi < 2; ++pi) {
                int p = 32 * w + 16 * pi + r15;                    // A row = lane%16
                a1v[pi] = *(const f16x4*)&A1[cur][p][4 * (4 * s + q)];
                a2v[pi] = *(const f16x4*)&A2[cur][p][4 * (4 * s + q)];
            }
            #pragma unroll
            for (int cj = 0; cj < 4; ++cj) {
                int n = 16 * cj + r15;                             // B col = lane%16
                b1v[cj] = *(const f16x4*)&B1[cur][n][4 * (4 * s + q)];
                b2v[cj] = *(const f16x4*)&B2[cur][n][4 * (4 * s + q)];
            }
            #pragma unroll
            for (int pi = 0; pi < 2; ++pi)
                #pragma unroll
                for (int cj = 0; cj < 4; ++cj) {
                    acc[pi][cj] = __builtin_amdgcn_mfma_f32_16x16x16f16(a2v[pi], b1v[cj], acc[pi][cj], 0, 0, 0);
                    acc[pi][cj] = __builtin_amdgcn_mfma_f32_16x16x16f16(a1v[pi], b2v[cj], acc[pi][cj], 0, 0, 0);
                    acc[pi][cj] = __builtin_amdgcn_mfma_f32_16x16x16f16(a1v[pi], b1v[cj], acc[pi][cj], 0, 0, 0);
                }
        }

        // ---- write prefetched chunk c+1 into the other buffer ----
        if (c + 1 < NCHUNK) {
            const int nxt = cur ^ 1;
            #pragma unroll
            for (int m = 0; m < 4; ++m) {
                *(f16x4*)&A1[nxt][rh][4 * (4 * hh + m)] = a[m].hi;
                *(f16x4*)&A2[nxt][rh][4 * (4 * hh + m)] = a[m].lo;
            }
            #pragma unroll
            for (int m = 0; m < 2; ++m) {
                *(f16x4*)&B1[nxt][cc][4 * (2 * jj + m)] = b[m].hi;
                *(f16x4*)&B2[nxt][cc][4 * (2 * jj + m)] = b[m].lo;
            }
        }
        __syncthreads();
        // ---- prefetch chunk c+2 ----
        if (c + 2 < NCHUNK) {
            const int q0 = 8 * (c + 2);
            #pragma unroll
            for (int m = 0; m < 4; ++m) { int qa = q0 + 4 * hh + m; a[m] = (qa < NQ) ? prow[qa] : hlzero(); }
            #pragma unroll
            for (int m = 0; m < 2; ++m) { int qb = q0 + 2 * jj + m; b[m] = (qb < NQ) ? crow[qb] : hlzero(); }
        }
    }

    // ---- argmax epilogue (ties -> lowest cluster, matches jnp.argmax) ----
    #pragma unroll
    for (int pi = 0; pi < 2; ++pi) {
        #pragma unroll
        for (int r = 0; r < 4; ++r) {
            float m  = acc[pi][0][r] - c2s[r15];
            int best = r15;
            #pragma unroll
            for (int cj = 1; cj < 4; ++cj) {
                int n = 16 * cj + r15;
                float s = acc[pi][cj][r] - c2s[n];
                if (s > m) { m = s; best = n; }
            }
            #pragma unroll
            for (int off = 1; off < 16; off <<= 1) {
                float om = __shfl_xor(m, off);
                int   ob = __shfl_xor(best, off);
                if (om > m || (om == m && ob < best)) { m = om; best = ob; }
            }
            if (r15 == 0) {
                int p  = 32 * w + 16 * pi + 4 * q + r;
                int np = n0 + p;
                if (np < NPTS) {
                    int rk = atomicAdd(&cnt[best], 1);   // LDS int rank
                    lr[(size_t)g * NPTS + np] = (unsigned short)((rk << 8) | best);
                }
            }
        }
    }
    __syncthreads();
    if (t < NK) pcnt[((size_t)g * NTILES + tile) * NK + t] = (unsigned char)cnt[t];
}

// ---------------------------------------------------------------------------
// Fused scan+scatter: stages pcnt[g] as u8 (20 KB, was 40), computes cluster
// totals, cbase, own-tile prefix, then scatters.
// ---------------------------------------------------------------------------
__global__ __launch_bounds__(256)
void scatter2_kernel(const unsigned short* __restrict__ lr,  // [NG][NPTS]
                     const unsigned char* __restrict__ pcnt, // [NG][NTILES][NK]
                     int* __restrict__ order,        // [NG][NPTS]
                     int* __restrict__ cbase,        // [NG][NK]
                     int* __restrict__ counts)       // [NG][NK]
{
    const int tile = blockIdx.x, g = blockIdx.y, t = threadIdx.x;
    __shared__ unsigned char cnt_tk[NTILES * NK];    // 20032 B
    __shared__ int part [4][NK];
    __shared__ int part2[4][NK];
    __shared__ int kbase[NK];
    __shared__ int tpre[NK];

    const unsigned int* pg32 = (const unsigned int*)(pcnt + (size_t)g * NTILES * NK);
    for (int i = t; i < NTILES * NK / 4; i += 256)
        ((unsigned int*)cnt_tk)[i] = pg32[i];
    __syncthreads();

    {   // 4-way split sums: totals and own-tile prefix per k
        int k = t & 63, p = t >> 6;
        int s1 = 0, s2 = 0;
        for (int tl = p; tl < NTILES; tl += 4) {
            int v = cnt_tk[tl * NK + k];
            s1 += v;
            if (tl < tile) s2 += v;
        }
        part [p][k] = s1;
        part2[p][k] = s2;
    }
    __syncthreads();
    if (t < NK) {
        part[0][t] = part[0][t] + part[1][t] + part[2][t] + part[3][t];   // totals
        tpre[t]    = part2[0][t] + part2[1][t] + part2[2][t] + part2[3][t];
    }
    __syncthreads();
    if (t == 0) {
        int run = 0;
        for (int k = 0; k < NK; ++k) { kbase[k] = run; run += part[0][k]; }
    }
    __syncthreads();
    if (tile == 0 && t < NK) {
        cbase[g * NK + t]  = kbase[t];
        counts[g * NK + t] = part[0][t];
    }
    const int n = tile * PT + t;
    if (t < PT && n < NPTS) {
        int packed = lr[(size_t)g * NPTS + n];
        int L = packed & 63, r = packed >> 8;
        order[(size_t)g * NPTS + kbase[L] + tpre[L] + r] = n;
    }
}

// ---------------------------------------------------------------------------
// Gather: block = (split, k, g). 5 points x 100 lanes, register acc over
// split rows (hi+lo, x64 scale), disjoint partial rows + tree add.
// ---------------------------------------------------------------------------
__global__ __launch_bounds__(512, 2)
void gather_kernel(const HL*  __restrict__ ps,      // [NG][NPTS][NQ]
                   const int* __restrict__ order,   // [NG][NPTS]
                   const int* __restrict__ cbase,   // [NG][NK]
                   const int* __restrict__ counts,  // [NG][NK]
                   float* __restrict__ psum)        // [NG][NK][NSPL][ND] (x64)
{
    const int s = blockIdx.x, k = blockIdx.y, g = blockIdx.z;
    const int t = threadIdx.x;
    const int base = cbase[g * NK + k];
    const int cnt  = counts[g * NK + k];
    const int start = base + (cnt * s) / NSPL;
    const int end   = base + (cnt * (s + 1)) / NSPL;

    const int slot = t / 100;          // 0..4 active (t<500)
    const int q    = t - slot * 100;   // d-quad 0..99

    __shared__ float sums[5][ND];      // 8 KB, disjoint per slot

    float4 acc = make_float4(0.f, 0.f, 0.f, 0.f);
    if (t < 500) {
        const int* ord = order + (size_t)g * NPTS;
        #pragma unroll 2
        for (int i = start + slot; i < end; i += 5) {
            int n = ord[i];
            HL h = ps[((size_t)g * NPTS + n) * NQ + q];
            acc.x += (float)h.hi[0] + (float)h.lo[0];
            acc.y += (float)h.hi[1] + (float)h.lo[1];
            acc.z += (float)h.hi[2] + (float)h.lo[2];
            acc.w += (float)h.hi[3] + (float)h.lo[3];
        }
        *(float4*)&sums[slot][4 * q] = acc;
    }
    __syncthreads();
    if (t < NQ) {
        float4 a0 = *(const float4*)&sums[0][4 * t];
        float4 a1 = *(const float4*)&sums[1][4 * t];
        float4 a2 = *(const float4*)&sums[2][4 * t];
        float4 a3 = *(const float4*)&sums[3][4 * t];
        float4 a4 = *(const float4*)&sums[4][4 * t];
        float4 o;
        o.x = a0.x + a1.x + a2.x + a3.x + a4.x;
        o.y = a0.y + a1.y + a2.y + a3.y + a4.y;
        o.z = a0.z + a1.z + a2.z + a3.z + a4.z;
        o.w = a0.w + a1.w + a2.w + a3.w + a4.w;
        float* dst = psum + (((size_t)(g * NK + k)) * NSPL + s) * ND + 4 * t;
        *(float4*)dst = o;
    }
}

// ---------------------------------------------------------------------------
// Update: reduce NSPL partials (x64 scale), divide, descale (x2^-6 exact),
// empty-in-any-group zeroing; emit fp32 centroids + f16 splits + c2.
// ---------------------------------------------------------------------------
__global__ __launch_bounds__(128)
void update_kernel(const float* __restrict__ psum,   // [NG][NK][NSPL][ND]
                   const int*   __restrict__ counts, // [NG][NK]
                   float* __restrict__ outc,         // [NG][NK][ND]
                   HL*    __restrict__ cs,           // [NG][NK][NQ]
                   float* __restrict__ c2g)          // [NG][NK]
{
    const int gk = blockIdx.x;
    const int g = gk >> 6, k = gk & 63;
    const int t = threadIdx.x;

    __shared__ float qp[NQ];
    __shared__ float p4[4];

    const bool bad = (counts[0 * NK + k] == 0) | (counts[1 * NK + k] == 0) |
                     (counts[2 * NK + k] == 0) | (counts[3 * NK + k] == 0);
    const int  c  = counts[g * NK + k];
    const float inv = 1.0f / (float)(c == 0 ? 1 : c);

    if (t < NQ) {
        float4 s = make_float4(0.f, 0.f, 0.f, 0.f);
        const float* p = psum + ((size_t)gk * NSPL) * ND + 4 * t;
        #pragma unroll
        for (int sp = 0; sp < NSPL; ++sp) {
            float4 v = *(const float4*)(p + (size_t)sp * ND);
            s.x += v.x; s.y += v.y; s.z += v.z; s.w += v.w;
        }
        float4 c64;   // 64 * centroid (exactly the split input scale)
        c64.x = bad ? 0.0f : s.x * inv;
        c64.y = bad ? 0.0f : s.y * inv;
        c64.z = bad ? 0.0f : s.z * inv;
        c64.w = bad ? 0.0f : s.w * inv;
        float4 o = make_float4(c64.x * 0.015625f, c64.y * 0.015625f,
                               c64.z * 0.015625f, c64.w * 0.015625f);
        *(float4*)(outc + (size_t)gk * ND + 4 * t) = o;
        _Float16 a0 = (_Float16)c64.x, a1 = (_Float16)c64.y,
                 a2 = (_Float16)c64.z, a3 = (_Float16)c64.w;
        HL h;
        h.hi = f16x4{a0, a1, a2, a3};
        h.lo = f16x4{(_Float16)(c64.x - (float)a0), (_Float16)(c64.y - (float)a1),
                     (_Float16)(c64.z - (float)a2), (_Float16)(c64.w - (float)a3)};
        cs[(size_t)gk * NQ + t] = h;
        qp[t] = fmaf(o.x, o.x, fmaf(o.y, o.y, fmaf(o.z, o.z, o.w * o.w)));
    }
    __syncthreads();
    if (t < 4) {
        float s = 0.0f;
        for (int i = 25 * t; i < 25 * t + 25; ++i) s += qp[i];
        p4[t] = s;
    }
    __syncthreads();
    if (t == 0) c2g[gk] = 2048.0f * (((p4[0] + p4[1]) + p4[2]) + p4[3]);
}

extern "C" void kernel_launch(void* const* d_in, const int* in_sizes, int n_in,
                              void* d_out, int out_size, void* d_ws, size_t ws_size,
                              hipStream_t stream)
{
    const float* patches = (const float*)d_in[0];
    const float* cinit   = (const float*)d_in[1];
    float* out = (float*)d_out;

    char* wp = (char*)d_ws;
    HL* PS = (HL*)wp;                wp += (size_t)NPTS * NG * NQ * sizeof(HL);  // 256 MB
    HL* CS = (HL*)wp;                wp += (size_t)NG * NK * NQ * sizeof(HL);    // 400 KB
    float* c2g = (float*)wp;         wp += (size_t)NG * NK * 4;
    float* centA = (float*)wp;       wp += (size_t)NG * NK * ND * 4;
    float* centB = (float*)wp;       wp += (size_t)NG * NK * ND * 4;
    int* order   = (int*)wp;         wp += (size_t)NG * NPTS * 4;
    int* cbase   = (int*)wp;         wp += (size_t)NG * NK * 4;
    int* counts  = (int*)wp;         wp += (size_t)NG * NK * 4;
    float* psum  = (float*)wp;       wp += (size_t)NG * NK * NSPL * ND * 4;      // 26.2 MB
    unsigned short* lr = (unsigned short*)wp;  wp += (size_t)NG * NPTS * 2;
    unsigned char* pcnt = (unsigned char*)wp;  // NG*NTILES*NK bytes

    prepass_kernel<<<4096, 256, 0, stream>>>(patches, PS);
    centprep_kernel<<<NG * NK, 128, 0, stream>>>(cinit, CS, c2g);

    for (int e = 0; e < 10; ++e) {
        assign_kernel<<<dim3(NTILES, NG), 256, 0, stream>>>(PS, CS, c2g, lr, pcnt);
        scatter2_kernel<<<dim3(NTILES, NG), 256, 0, stream>>>(lr, pcnt, order, cbase, counts);
        gather_kernel<<<dim3(NSPL, NK, NG), 512, 0, stream>>>(PS, order, cbase, counts, psum);
        float* nxt = (e == 9) ? out : ((e & 1) ? centB : centA);
        update_kernel<<<NG * NK, 128, 0, stream>>>(psum, counts, nxt, CS, c2g);
    }
}